// Round 3
// 275.137 us; speedup vs baseline: 1.0092x; 1.0092x over previous
//
#include <hip/hip_runtime.h>
#include <hip/hip_fp16.h>

#define DIM 256
#define MARGIN 2.25e-4f

typedef __bf16 bf8v __attribute__((ext_vector_type(8)));
typedef float f4v __attribute__((ext_vector_type(4)));

__device__ inline unsigned short f2bf(float x) {
    unsigned u = __float_as_uint(x);
    u += 0x7fffu + ((u >> 16) & 1u);   // RNE
    return (unsigned short)(u >> 16);
}

// ---------------- fused prep ----------------
// [0,2048):    transpose z -> zf fp32 + zb bf16
// [2048,6144): emb -> eb bf16 + enorm
// 6144:        zero out_loss (d_out is poisoned before every launch)
__global__ __launch_bounds__(256) void k_prep(const float* __restrict__ z,
                                              const float* __restrict__ emb,
                                              float* __restrict__ zf,
                                              unsigned short* __restrict__ zb,
                                              unsigned short* __restrict__ eb,
                                              float* __restrict__ enorm,
                                              float* __restrict__ out_loss) {
    const int bx = blockIdx.x;
    if (bx < 2048) {
        __shared__ float tt[32][33];
        const int hw0 = (bx & 31) * 32;
        const int d0  = ((bx >> 5) & 7) * 32;
        const int b   = bx >> 8;
        const int tx = threadIdx.x & 31, ty = threadIdx.x >> 5;
#pragma unroll
        for (int i = 0; i < 4; i++) {
            const int d = d0 + ty + 8 * i;
            tt[ty + 8 * i][tx] = z[(b * 256 + d) * 1024 + hw0 + tx];
        }
        __syncthreads();
#pragma unroll
        for (int i = 0; i < 4; i++) {
            const int hw = hw0 + ty + 8 * i;
            const float v = tt[tx][ty + 8 * i];
            const size_t o = (size_t)(b * 1024 + hw) * DIM + d0 + tx;
            zf[o] = v;
            zb[o] = f2bf(v);
        }
    } else if (bx < 6144) {
        const int s = bx - 2048;
        const int wave = threadIdx.x >> 6, lane = threadIdx.x & 63;
        const int row = s * 4 + wave;
        const float4 v = *(const float4*)(emb + (size_t)row * DIM + lane * 4);
        ushort4 o;
        o.x = f2bf(v.x); o.y = f2bf(v.y); o.z = f2bf(v.z); o.w = f2bf(v.w);
        *(ushort4*)(eb + (size_t)row * DIM + lane * 4) = o;
        float ss = v.x * v.x + v.y * v.y + v.z * v.z + v.w * v.w;
#pragma unroll
        for (int m = 1; m < 64; m <<= 1) ss += __shfl_xor(ss, m, 64);
        if (lane == 0) enorm[row] = ss;
    } else {
        if (threadIdx.x == 0) out_loss[0] = 0.f;
    }
}

// ---------------- bf16 MFMA scoring ----------------
// R11: software-pipelined inner loop; same tiling / swizzle / group mapping as R10.
// Group g = by*16 + wc*4 + (m15>>2): codes by*256 + wc*64 + ct*16 + (m15>>2)*4 + l
#define LOADA(kk, s) { \
    const int slot_ = ((((kk) * 4) + q) ^ m15) * 8; \
    Ap[s][0] = *(const bf8v*)&As[(m15)      * 256 + slot_]; \
    Ap[s][1] = *(const bf8v*)&As[(16 + m15) * 256 + slot_]; \
    Ap[s][2] = *(const bf8v*)&As[(32 + m15) * 256 + slot_]; \
    Ap[s][3] = *(const bf8v*)&As[(48 + m15) * 256 + slot_]; }

#define LOADB(kk, s) { \
    Bp[s][0] = *(const bf8v*)(brow +            (kk) * 32); \
    Bp[s][1] = *(const bf8v*)(brow + 16 * DIM + (kk) * 32); \
    Bp[s][2] = *(const bf8v*)(brow + 32 * DIM + (kk) * 32); \
    Bp[s][3] = *(const bf8v*)(brow + 48 * DIM + (kk) * 32); }

__global__ __launch_bounds__(256, 3) void k_score(
        const unsigned short* __restrict__ zb, const unsigned short* __restrict__ eb,
        const float* __restrict__ enorm, unsigned short* __restrict__ pvalh) {
    __shared__ unsigned short As[64 * 256];   // 32 KB, swizzled: slot = chunk ^ (r&15)
    __shared__ unsigned short sm[64 * 16];    // 2 KB
    const int rx = blockIdx.x & 127;
    const int by = blockIdx.x >> 7;
    const int row0 = rx * 64;
    const int col0 = by * 256;
    const int t = threadIdx.x;
    const int lane = t & 63, wc = t >> 6;
    const int q = lane >> 4, m15 = lane & 15;

#pragma unroll
    for (int j = 0; j < 8; j++) {
        const int id = j * 256 + t;
        const int r = id >> 5, sl = id & 31;
        const int c = sl ^ (r & 15);
        __builtin_amdgcn_global_load_lds(
            (const __attribute__((address_space(1))) void*)(zb + (size_t)(row0 + r) * DIM + c * 8),
            (__attribute__((address_space(3))) void*)((char*)As + id * 16), 16, 0, 0);
    }
    __syncthreads();

    f4v acc[4][4];
#pragma unroll
    for (int rt = 0; rt < 4; rt++)
#pragma unroll
        for (int ct = 0; ct < 4; ct++) acc[rt][ct] = (f4v){0.f, 0.f, 0.f, 0.f};

    const unsigned short* brow = eb + (size_t)(col0 + wc * 64 + m15) * DIM + q * 8;

    // software-pipelined K loop: A depth-2 (LDS), B depth-3 (global/L2)
    bf8v Ap[2][4], Bp[3][4];
    LOADB(0, 0)
    LOADB(1, 1)
    LOADA(0, 0)
#pragma unroll
    for (int kk = 0; kk < 8; kk++) {
        if (kk + 2 < 8) LOADB(kk + 2, (kk + 2) % 3)
        if (kk + 1 < 8) LOADA(kk + 1, (kk + 1) & 1)
        __builtin_amdgcn_s_setprio(1);
#pragma unroll
        for (int rt = 0; rt < 4; rt++)
#pragma unroll
            for (int ct = 0; ct < 4; ct++)
                acc[rt][ct] = __builtin_amdgcn_mfma_f32_16x16x32_bf16(
                    Ap[kk & 1][rt], Bp[kk % 3][ct], acc[rt][ct], 0, 0, 0);
        __builtin_amdgcn_s_setprio(0);
    }

    float en_l[4];
#pragma unroll
    for (int ct = 0; ct < 4; ct++) en_l[ct] = enorm[col0 + wc * 64 + ct * 16 + m15];
    const int gsl = wc * 4 + (m15 >> 2);
#pragma unroll
    for (int rt = 0; rt < 4; rt++) {
        float sv[4];
#pragma unroll
        for (int j = 0; j < 4; j++) {
            float s = fmaf(-2.f, acc[rt][0][j], en_l[0]);
#pragma unroll
            for (int ct = 1; ct < 4; ct++)
                s = fminf(s, fmaf(-2.f, acc[rt][ct][j], en_l[ct]));
            sv[j] = s;
        }
#pragma unroll
        for (int m = 1; m <= 2; m <<= 1)
#pragma unroll
            for (int j = 0; j < 4; j++)
                sv[j] = fminf(sv[j], __shfl_xor(sv[j], m, 64));
        if ((m15 & 3) == 0) {
            const int rl = rt * 16 + q * 4;
#pragma unroll
            for (int j = 0; j < 4; j++)
                sm[(rl + j) * 16 + gsl] = __half_as_ushort(__float2half_rn(sv[j]));
        }
    }
    __syncthreads();
    if (t < 128) {
        const uint4 v = *(const uint4*)&sm[t * 8];
        *(uint4*)&pvalh[(size_t)(row0 + (t >> 1)) * 1024 + by * 16 + (t & 1) * 8] = v;
    }
}

// ---------------- select: per-row flag + exact fp32 rescore + argmin ----------------
__global__ __launch_bounds__(256) void k_select(
        const float* __restrict__ zf, const float* __restrict__ emb,
        const float* __restrict__ enorm, const unsigned short* __restrict__ pvalh,
        int* __restrict__ idxi, float* __restrict__ out_idx) {
    const int row = blockIdx.x;
    const int t = threadIdx.x;
    const int lane = t & 63, w = t >> 6;
    __shared__ float zs[256];
    __shared__ float wred[4];
    __shared__ int lcnt;
    __shared__ int list[1024];
    __shared__ float fs[16];
    __shared__ int fi[16];

    const float zv = zf[(size_t)row * DIM + t];
    zs[t] = zv;
    if (t == 0) lcnt = 0;
    float nrm = zv * zv;
#pragma unroll
    for (int m = 1; m < 64; m <<= 1) nrm += __shfl_xor(nrm, m, 64);
    if (lane == 0) wred[w] = nrm;

    const __half* p = (const __half*)(pvalh + (size_t)row * 1024 + t * 4);
    float v[4];
#pragma unroll
    for (int k = 0; k < 4; k++) v[k] = __half2float(p[k]);
    float mn = fminf(fminf(v[0], v[1]), fminf(v[2], v[3]));
#pragma unroll
    for (int m = 1; m < 64; m <<= 1) mn = fminf(mn, __shfl_xor(mn, m, 64));
    __shared__ float wmin[4];
    if (lane == 0) wmin[w] = mn;
    __syncthreads();
    const float zn = wred[0] + wred[1] + wred[2] + wred[3];
    const float g = fminf(fminf(wmin[0], wmin[1]), fminf(wmin[2], wmin[3])) + MARGIN;
#pragma unroll
    for (int k = 0; k < 4; k++) {
        if (v[k] <= g) {
            const int pos = atomicAdd(&lcnt, 1);
            list[pos] = t * 4 + k;
        }
    }
    __syncthreads();

    const int lane16 = t & 15, codei = t >> 4;
    const int n = lcnt;
    float bv = 3.0e38f;
    int bi = 0x7fffffff;
    for (int i = 0; i < n; i++) {
        const int gg = list[i];
        const int cbase = ((gg >> 4) << 8) + (((gg >> 2) & 3) << 6) + ((gg & 3) << 2);
        const int code = cbase + ((codei >> 2) << 4) + (codei & 3);
        const float* zp = zs + lane16 * 16;
        const float* ep = emb + (size_t)code * DIM + lane16 * 16;
        float d = 0.f;
#pragma unroll
        for (int k = 0; k < 16; k += 4) {
            const float4 ev = *(const float4*)(ep + k);
            const float4 zv4 = *(const float4*)(zp + k);
            d = fmaf(zv4.x, ev.x, d);
            d = fmaf(zv4.y, ev.y, d);
            d = fmaf(zv4.z, ev.z, d);
            d = fmaf(zv4.w, ev.w, d);
        }
#pragma unroll
        for (int m = 1; m <= 8; m <<= 1) d += __shfl_xor(d, m, 64);
        if (lane16 == 0) {
            const float tt = zn + enorm[code];
            const float s = tt - 2.0f * d;
            if (s < bv || (s == bv && code < bi)) { bv = s; bi = code; }
        }
    }
    if (lane16 == 0) { fs[codei] = bv; fi[codei] = bi; }
    __syncthreads();
    if (t == 0) {
        float b = fs[0]; int c = fi[0];
#pragma unroll
        for (int k = 1; k < 16; k++)
            if (fs[k] < b || (fs[k] == b && fi[k] < c)) { b = fs[k]; c = fi[k]; }
        idxi[row] = c;
        out_idx[row] = (float)c;
    }
}

// ---------------- gather z_q (NCHW) + fused loss (atomicAdd) ----------------
__global__ __launch_bounds__(256) void k_gather(const float* __restrict__ emb,
                                                const float* __restrict__ zf,
                                                const int* __restrict__ idxi,
                                                float* __restrict__ zq,
                                                float* __restrict__ out_loss) {
    __shared__ float t[32][33];
    const int hw0 = blockIdx.x * 32;
    const int c0  = blockIdx.y * 32;
    const int b   = blockIdx.z;
    const int tx = threadIdx.x & 31, ty = threadIdx.x >> 5;
    float lsum = 0.f;
#pragma unroll
    for (int i = 0; i < 4; i++) {
        const int hh = ty + 8 * i;
        const int n = b * 1024 + hw0 + hh;
        const int id = idxi[n];
        const float q = emb[(size_t)id * DIM + c0 + tx];
        const float zv = zf[(size_t)n * DIM + c0 + tx];
        const float d = q - zv;
        lsum += d * d;
        t[hh][tx] = q;
    }
    __syncthreads();
#pragma unroll
    for (int i = 0; i < 4; i++) {
        const int c = c0 + ty + 8 * i;
        zq[(size_t)(b * 256 + c) * 1024 + hw0 + tx] = t[tx][ty + 8 * i];
    }
#pragma unroll
    for (int m = 1; m < 64; m <<= 1) lsum += __shfl_xor(lsum, m, 64);
    __shared__ float wsum[4];
    const int lane = threadIdx.x & 63, w = threadIdx.x >> 6;
    if (lane == 0) wsum[w] = lsum;
    __syncthreads();
    if (threadIdx.x == 0) {
        const float total = wsum[0] + wsum[1] + wsum[2] + wsum[3];
        atomicAdd(out_loss, total * (1.25f / 2097152.0f));
    }
}

extern "C" void kernel_launch(void* const* d_in, const int* in_sizes, int n_in,
                              void* d_out, int out_size, void* d_ws, size_t ws_size,
                              hipStream_t stream) {
    const float* z   = (const float*)d_in[0];   // [8,256,32,32]
    const float* emb = (const float*)d_in[1];   // [16384,256]
    float* out = (float*)d_out;
    float* ws  = (float*)d_ws;

    float*          zf    = ws;                                   // 2,097,152 floats (8 MB)
    unsigned short* pvalh = (unsigned short*)(ws + 2097152);      // 8M halves (16 MB)
    unsigned short* zb    = (unsigned short*)(ws + 6291456);      // 2M halves (4 MB)
    unsigned short* eb    = (unsigned short*)(ws + 7340032);      // 4M halves (8 MB)
    float*          enorm = ws + 9437184;                         // 16,384
    int*            idxi  = (int*)(ws + 9453568);                 // 8,192

    float* zq       = out;                   // [8,256,32,32] NCHW
    float* out_loss = out + 2097152;         // scalar
    float* out_idx  = out + 2097153;         // [8192] as float32

    k_prep<<<dim3(6145), 256, 0, stream>>>(z, emb, zf, zb, eb, enorm, out_loss);
    k_score<<<dim3(8192), 256, 0, stream>>>(zb, eb, enorm, pvalh);
    k_select<<<dim3(8192), 256, 0, stream>>>(zf, emb, enorm, pvalh, idxi, out_idx);
    k_gather<<<dim3(32, 8, 8), 256, 0, stream>>>(emb, zf, idxi, zq, out_loss);
}

// Round 4
// 274.059 us; speedup vs baseline: 1.0131x; 1.0039x over previous
//
#include <hip/hip_runtime.h>
#include <hip/hip_fp16.h>

#define DIM 256
#define MARGIN 2.25e-4f

typedef __bf16 bf8v __attribute__((ext_vector_type(8)));
typedef float f4v __attribute__((ext_vector_type(4)));

__device__ inline unsigned short f2bf(float x) {
    unsigned u = __float_as_uint(x);
    u += 0x7fffu + ((u >> 16) & 1u);   // RNE
    return (unsigned short)(u >> 16);
}

// ---------------- fused prep ----------------
// [0,2048):    transpose z -> zf fp32 + zb bf16
// [2048,6144): emb -> eb bf16 + enorm
// 6144:        zero out_loss (d_out is poisoned before every launch)
__global__ __launch_bounds__(256) void k_prep(const float* __restrict__ z,
                                              const float* __restrict__ emb,
                                              float* __restrict__ zf,
                                              unsigned short* __restrict__ zb,
                                              unsigned short* __restrict__ eb,
                                              float* __restrict__ enorm,
                                              float* __restrict__ out_loss) {
    const int bx = blockIdx.x;
    if (bx < 2048) {
        __shared__ float tt[32][33];
        const int hw0 = (bx & 31) * 32;
        const int d0  = ((bx >> 5) & 7) * 32;
        const int b   = bx >> 8;
        const int tx = threadIdx.x & 31, ty = threadIdx.x >> 5;
#pragma unroll
        for (int i = 0; i < 4; i++) {
            const int d = d0 + ty + 8 * i;
            tt[ty + 8 * i][tx] = z[(b * 256 + d) * 1024 + hw0 + tx];
        }
        __syncthreads();
#pragma unroll
        for (int i = 0; i < 4; i++) {
            const int hw = hw0 + ty + 8 * i;
            const float v = tt[tx][ty + 8 * i];
            const size_t o = (size_t)(b * 1024 + hw) * DIM + d0 + tx;
            zf[o] = v;
            zb[o] = f2bf(v);
        }
    } else if (bx < 6144) {
        const int s = bx - 2048;
        const int wave = threadIdx.x >> 6, lane = threadIdx.x & 63;
        const int row = s * 4 + wave;
        const float4 v = *(const float4*)(emb + (size_t)row * DIM + lane * 4);
        ushort4 o;
        o.x = f2bf(v.x); o.y = f2bf(v.y); o.z = f2bf(v.z); o.w = f2bf(v.w);
        *(ushort4*)(eb + (size_t)row * DIM + lane * 4) = o;
        float ss = v.x * v.x + v.y * v.y + v.z * v.z + v.w * v.w;
#pragma unroll
        for (int m = 1; m < 64; m <<= 1) ss += __shfl_xor(ss, m, 64);
        if (lane == 0) enorm[row] = ss;
    } else {
        if (threadIdx.x == 0) out_loss[0] = 0.f;
    }
}

// ---------------- bf16 MFMA scoring ----------------
// R12: inline-asm depth-3 B pipeline with hand-counted vmcnt (T4).
// R11 lesson: C-level prefetch gets sunk by the scheduler (VGPR stayed 80, util 20%).
// Here the loads are asm volatile (un-sinkable) and the waits are counted:
//   prologue issues stages 0..2 (12 loads); iter kk waits vmcnt(8) (oldest stage done),
//   computes, then issues stage kk+3 into slot kk%3. Tail: vmcnt(4), vmcnt(0).
// sched_barrier(0) after each waitcnt pins MFMAs behind it (rule #18).
// Group g = by*16 + wc*4 + (m15>>2): codes by*256 + wc*64 + ct*16 + (m15>>2)*4 + l
#define GLOADB(dst, voff, base) \
    asm volatile("global_load_dwordx4 %0, %1, %2" : "=&v"(dst) : "v"(voff), "s"(base))
#define WAITV(n) asm volatile("s_waitcnt vmcnt(" #n ")" ::: "memory")

__global__ __launch_bounds__(256, 3) void k_score(
        const unsigned short* __restrict__ zb, const unsigned short* __restrict__ eb,
        const float* __restrict__ enorm, unsigned short* __restrict__ pvalh) {
    __shared__ unsigned short As[64 * 256];   // 32 KB, swizzled: slot = chunk ^ (r&15)
    __shared__ unsigned short sm[64 * 16];    // 2 KB
    const int rx = blockIdx.x & 127;
    const int by = blockIdx.x >> 7;
    const int row0 = rx * 64;
    const int col0 = by * 256;
    const int t = threadIdx.x;
    const int lane = t & 63, wc = t >> 6;
    const int q = lane >> 4, m15 = lane & 15;

#pragma unroll
    for (int j = 0; j < 8; j++) {
        const int id = j * 256 + t;
        const int r = id >> 5, sl = id & 31;
        const int c = sl ^ (r & 15);
        __builtin_amdgcn_global_load_lds(
            (const __attribute__((address_space(1))) void*)(zb + (size_t)(row0 + r) * DIM + c * 8),
            (__attribute__((address_space(3))) void*)((char*)As + id * 16), 16, 0, 0);
    }
    __syncthreads();   // drains vmcnt to 0 -> clean slate for hand-counted waits

    f4v acc[4][4];
#pragma unroll
    for (int rt = 0; rt < 4; rt++)
#pragma unroll
        for (int ct = 0; ct < 4; ct++) acc[rt][ct] = (f4v){0.f, 0.f, 0.f, 0.f};

    // byte voffsets into eb for the 4 ct-fragments of this lane (stage s adds s*64 bytes)
    unsigned voffb[4];
#pragma unroll
    for (int ct = 0; ct < 4; ct++)
        voffb[ct] = (unsigned)(((col0 + wc * 64 + ct * 16 + m15) * DIM + q * 8) * 2);

    bf8v Bp[3][4];
    // prologue: issue stages 0,1,2 (12 loads in flight)
#pragma unroll
    for (int s = 0; s < 3; s++)
#pragma unroll
        for (int ct = 0; ct < 4; ct++)
            GLOADB(Bp[s][ct], voffb[ct] + (unsigned)(s * 64), eb);

#pragma unroll
    for (int kk = 0; kk < 8; kk++) {
        if (kk < 6)      { WAITV(8); }
        else if (kk == 6){ WAITV(4); }
        else             { WAITV(0); }
        __builtin_amdgcn_sched_barrier(0);

        bf8v af[4];
        {
            const int slot_ = ((kk * 4 + q) ^ m15) * 8;
            af[0] = *(const bf8v*)&As[(m15)      * 256 + slot_];
            af[1] = *(const bf8v*)&As[(16 + m15) * 256 + slot_];
            af[2] = *(const bf8v*)&As[(32 + m15) * 256 + slot_];
            af[3] = *(const bf8v*)&As[(48 + m15) * 256 + slot_];
        }
        __builtin_amdgcn_s_setprio(1);
#pragma unroll
        for (int rt = 0; rt < 4; rt++)
#pragma unroll
            for (int ct = 0; ct < 4; ct++)
                acc[rt][ct] = __builtin_amdgcn_mfma_f32_16x16x32_bf16(
                    af[rt], Bp[kk % 3][ct], acc[rt][ct], 0, 0, 0);
        __builtin_amdgcn_s_setprio(0);

        if (kk + 3 < 8) {
#pragma unroll
            for (int ct = 0; ct < 4; ct++)
                GLOADB(Bp[kk % 3][ct], voffb[ct] + (unsigned)((kk + 3) * 64), eb);
        }
    }

    float en_l[4];
#pragma unroll
    for (int ct = 0; ct < 4; ct++) en_l[ct] = enorm[col0 + wc * 64 + ct * 16 + m15];
    const int gsl = wc * 4 + (m15 >> 2);
#pragma unroll
    for (int rt = 0; rt < 4; rt++) {
        float sv[4];
#pragma unroll
        for (int j = 0; j < 4; j++) {
            float s = fmaf(-2.f, acc[rt][0][j], en_l[0]);
#pragma unroll
            for (int ct = 1; ct < 4; ct++)
                s = fminf(s, fmaf(-2.f, acc[rt][ct][j], en_l[ct]));
            sv[j] = s;
        }
#pragma unroll
        for (int m = 1; m <= 2; m <<= 1)
#pragma unroll
            for (int j = 0; j < 4; j++)
                sv[j] = fminf(sv[j], __shfl_xor(sv[j], m, 64));
        if ((m15 & 3) == 0) {
            const int rl = rt * 16 + q * 4;
#pragma unroll
            for (int j = 0; j < 4; j++)
                sm[(rl + j) * 16 + gsl] = __half_as_ushort(__float2half_rn(sv[j]));
        }
    }
    __syncthreads();
    if (t < 128) {
        const uint4 v = *(const uint4*)&sm[t * 8];
        *(uint4*)&pvalh[(size_t)(row0 + (t >> 1)) * 1024 + by * 16 + (t & 1) * 8] = v;
    }
}

// ---------------- select: per-row flag + exact fp32 rescore + argmin ----------------
__global__ __launch_bounds__(256) void k_select(
        const float* __restrict__ zf, const float* __restrict__ emb,
        const float* __restrict__ enorm, const unsigned short* __restrict__ pvalh,
        int* __restrict__ idxi, float* __restrict__ out_idx) {
    const int row = blockIdx.x;
    const int t = threadIdx.x;
    const int lane = t & 63, w = t >> 6;
    __shared__ float zs[256];
    __shared__ float wred[4];
    __shared__ int lcnt;
    __shared__ int list[1024];
    __shared__ float fs[16];
    __shared__ int fi[16];

    const float zv = zf[(size_t)row * DIM + t];
    zs[t] = zv;
    if (t == 0) lcnt = 0;
    float nrm = zv * zv;
#pragma unroll
    for (int m = 1; m < 64; m <<= 1) nrm += __shfl_xor(nrm, m, 64);
    if (lane == 0) wred[w] = nrm;

    const __half* p = (const __half*)(pvalh + (size_t)row * 1024 + t * 4);
    float v[4];
#pragma unroll
    for (int k = 0; k < 4; k++) v[k] = __half2float(p[k]);
    float mn = fminf(fminf(v[0], v[1]), fminf(v[2], v[3]));
#pragma unroll
    for (int m = 1; m < 64; m <<= 1) mn = fminf(mn, __shfl_xor(mn, m, 64));
    __shared__ float wmin[4];
    if (lane == 0) wmin[w] = mn;
    __syncthreads();
    const float zn = wred[0] + wred[1] + wred[2] + wred[3];
    const float g = fminf(fminf(wmin[0], wmin[1]), fminf(wmin[2], wmin[3])) + MARGIN;
#pragma unroll
    for (int k = 0; k < 4; k++) {
        if (v[k] <= g) {
            const int pos = atomicAdd(&lcnt, 1);
            list[pos] = t * 4 + k;
        }
    }
    __syncthreads();

    const int lane16 = t & 15, codei = t >> 4;
    const int n = lcnt;
    float bv = 3.0e38f;
    int bi = 0x7fffffff;
    for (int i = 0; i < n; i++) {
        const int gg = list[i];
        const int cbase = ((gg >> 4) << 8) + (((gg >> 2) & 3) << 6) + ((gg & 3) << 2);
        const int code = cbase + ((codei >> 2) << 4) + (codei & 3);
        const float* zp = zs + lane16 * 16;
        const float* ep = emb + (size_t)code * DIM + lane16 * 16;
        float d = 0.f;
#pragma unroll
        for (int k = 0; k < 16; k += 4) {
            const float4 ev = *(const float4*)(ep + k);
            const float4 zv4 = *(const float4*)(zp + k);
            d = fmaf(zv4.x, ev.x, d);
            d = fmaf(zv4.y, ev.y, d);
            d = fmaf(zv4.z, ev.z, d);
            d = fmaf(zv4.w, ev.w, d);
        }
#pragma unroll
        for (int m = 1; m <= 8; m <<= 1) d += __shfl_xor(d, m, 64);
        if (lane16 == 0) {
            const float tt = zn + enorm[code];
            const float s = tt - 2.0f * d;
            if (s < bv || (s == bv && code < bi)) { bv = s; bi = code; }
        }
    }
    if (lane16 == 0) { fs[codei] = bv; fi[codei] = bi; }
    __syncthreads();
    if (t == 0) {
        float b = fs[0]; int c = fi[0];
#pragma unroll
        for (int k = 1; k < 16; k++)
            if (fs[k] < b || (fs[k] == b && fi[k] < c)) { b = fs[k]; c = fi[k]; }
        idxi[row] = c;
        out_idx[row] = (float)c;
    }
}

// ---------------- gather z_q (NCHW) + fused loss (atomicAdd) ----------------
__global__ __launch_bounds__(256) void k_gather(const float* __restrict__ emb,
                                                const float* __restrict__ zf,
                                                const int* __restrict__ idxi,
                                                float* __restrict__ zq,
                                                float* __restrict__ out_loss) {
    __shared__ float t[32][33];
    const int hw0 = blockIdx.x * 32;
    const int c0  = blockIdx.y * 32;
    const int b   = blockIdx.z;
    const int tx = threadIdx.x & 31, ty = threadIdx.x >> 5;
    float lsum = 0.f;
#pragma unroll
    for (int i = 0; i < 4; i++) {
        const int hh = ty + 8 * i;
        const int n = b * 1024 + hw0 + hh;
        const int id = idxi[n];
        const float q = emb[(size_t)id * DIM + c0 + tx];
        const float zv = zf[(size_t)n * DIM + c0 + tx];
        const float d = q - zv;
        lsum += d * d;
        t[hh][tx] = q;
    }
    __syncthreads();
#pragma unroll
    for (int i = 0; i < 4; i++) {
        const int c = c0 + ty + 8 * i;
        zq[(size_t)(b * 256 + c) * 1024 + hw0 + tx] = t[tx][ty + 8 * i];
    }
#pragma unroll
    for (int m = 1; m < 64; m <<= 1) lsum += __shfl_xor(lsum, m, 64);
    __shared__ float wsum[4];
    const int lane = threadIdx.x & 63, w = threadIdx.x >> 6;
    if (lane == 0) wsum[w] = lsum;
    __syncthreads();
    if (threadIdx.x == 0) {
        const float total = wsum[0] + wsum[1] + wsum[2] + wsum[3];
        atomicAdd(out_loss, total * (1.25f / 2097152.0f));
    }
}

extern "C" void kernel_launch(void* const* d_in, const int* in_sizes, int n_in,
                              void* d_out, int out_size, void* d_ws, size_t ws_size,
                              hipStream_t stream) {
    const float* z   = (const float*)d_in[0];   // [8,256,32,32]
    const float* emb = (const float*)d_in[1];   // [16384,256]
    float* out = (float*)d_out;
    float* ws  = (float*)d_ws;

    float*          zf    = ws;                                   // 2,097,152 floats (8 MB)
    unsigned short* pvalh = (unsigned short*)(ws + 2097152);      // 8M halves (16 MB)
    unsigned short* zb    = (unsigned short*)(ws + 6291456);      // 2M halves (4 MB)
    unsigned short* eb    = (unsigned short*)(ws + 7340032);      // 4M halves (8 MB)
    float*          enorm = ws + 9437184;                         // 16,384
    int*            idxi  = (int*)(ws + 9453568);                 // 8,192

    float* zq       = out;                   // [8,256,32,32] NCHW
    float* out_loss = out + 2097152;         // scalar
    float* out_idx  = out + 2097153;         // [8192] as float32

    k_prep<<<dim3(6145), 256, 0, stream>>>(z, emb, zf, zb, eb, enorm, out_loss);
    k_score<<<dim3(8192), 256, 0, stream>>>(zb, eb, enorm, pvalh);
    k_select<<<dim3(8192), 256, 0, stream>>>(zf, emb, enorm, pvalh, idxi, out_idx);
    k_gather<<<dim3(32, 8, 8), 256, 0, stream>>>(emb, zf, idxi, zq, out_loss);
}

// Round 7
// 272.955 us; speedup vs baseline: 1.0172x; 1.0040x over previous
//
#include <hip/hip_runtime.h>
#include <hip/hip_fp16.h>

#define DIM 256
#define MARGIN 2.25e-4f

typedef __bf16 bf8v __attribute__((ext_vector_type(8)));
typedef float f4v __attribute__((ext_vector_type(4)));

__device__ inline unsigned short f2bf(float x) {
    unsigned u = __float_as_uint(x);
    u += 0x7fffu + ((u >> 16) & 1u);   // RNE
    return (unsigned short)(u >> 16);
}

// ---------------- fused prep ----------------
__global__ __launch_bounds__(256) void k_prep(const float* __restrict__ z,
                                              const float* __restrict__ emb,
                                              float* __restrict__ zf,
                                              unsigned short* __restrict__ zb,
                                              unsigned short* __restrict__ eb,
                                              float* __restrict__ enorm,
                                              float* __restrict__ out_loss) {
    const int bx = blockIdx.x;
    if (bx < 2048) {
        __shared__ float tt[32][33];
        const int hw0 = (bx & 31) * 32;
        const int d0  = ((bx >> 5) & 7) * 32;
        const int b   = bx >> 8;
        const int tx = threadIdx.x & 31, ty = threadIdx.x >> 5;
#pragma unroll
        for (int i = 0; i < 4; i++) {
            const int d = d0 + ty + 8 * i;
            tt[ty + 8 * i][tx] = z[(b * 256 + d) * 1024 + hw0 + tx];
        }
        __syncthreads();
#pragma unroll
        for (int i = 0; i < 4; i++) {
            const int hw = hw0 + ty + 8 * i;
            const float v = tt[tx][ty + 8 * i];
            const size_t o = (size_t)(b * 1024 + hw) * DIM + d0 + tx;
            zf[o] = v;
            zb[o] = f2bf(v);
        }
    } else if (bx < 6144) {
        const int s = bx - 2048;
        const int wave = threadIdx.x >> 6, lane = threadIdx.x & 63;
        const int row = s * 4 + wave;
        const float4 v = *(const float4*)(emb + (size_t)row * DIM + lane * 4);
        ushort4 o;
        o.x = f2bf(v.x); o.y = f2bf(v.y); o.z = f2bf(v.z); o.w = f2bf(v.w);
        *(ushort4*)(eb + (size_t)row * DIM + lane * 4) = o;
        float ss = v.x * v.x + v.y * v.y + v.z * v.z + v.w * v.w;
#pragma unroll
        for (int m = 1; m < 64; m <<= 1) ss += __shfl_xor(ss, m, 64);
        if (lane == 0) enorm[row] = ss;
    } else {
        if (threadIdx.x == 0) out_loss[0] = 0.f;
    }
}

// ---------------- bf16 MFMA scoring ----------------
// R15: static 4-panel schedule (as R14) with ONE change: enorm comes from LDS
// (staged via global_load_lds, read via ds_read inside EPI -> lgkmcnt only,
// vmcnt FIFO untouched), removing 16 long-lived VGPRs. Theory: R13/R14's garbage
// idx was a register SPILL injecting scratch buffer-stores into the hand-counted
// vmcnt FIFO (scratch store = silent count corruption; R12 fit in 68 regs, the
// en_all pin + 4-panel liveness pushed past the (256,3)=170 budget).
#define GLOADB(dst, voff, base) \
    asm volatile("global_load_dwordx4 %0, %1, %2" : "=&v"(dst) : "v"(voff), "s"(base))
#define SO(KK) ((unsigned)((((KK) >> 3) * 131072) + (((KK) & 7) * 64)))

#define ISSUE(sl, KK) \
    GLOADB(Bp##sl##_0, voffb0 + SO(KK), eb); \
    GLOADB(Bp##sl##_1, voffb1 + SO(KK), eb); \
    GLOADB(Bp##sl##_2, voffb2 + SO(KK), eb); \
    GLOADB(Bp##sl##_3, voffb3 + SO(KK), eb);

#define MFMA4(rt, AF, sl) \
    acc[rt][0] = __builtin_amdgcn_mfma_f32_16x16x32_bf16(AF, Bp##sl##_0, acc[rt][0], 0, 0, 0); \
    acc[rt][1] = __builtin_amdgcn_mfma_f32_16x16x32_bf16(AF, Bp##sl##_1, acc[rt][1], 0, 0, 0); \
    acc[rt][2] = __builtin_amdgcn_mfma_f32_16x16x32_bf16(AF, Bp##sl##_2, acc[rt][2], 0, 0, 0); \
    acc[rt][3] = __builtin_amdgcn_mfma_f32_16x16x32_bf16(AF, Bp##sl##_3, acc[rt][3], 0, 0, 0);

#define STEP(kk, sl, wv) { \
    asm volatile("s_waitcnt vmcnt(" #wv ")" ::: "memory"); \
    __builtin_amdgcn_sched_barrier(0); \
    const int slot_ = (((kk) * 4 + q) ^ m15) * 8; \
    const bf8v af0 = *(const bf8v*)&As[(m15)      * 256 + slot_]; \
    const bf8v af1 = *(const bf8v*)&As[(16 + m15) * 256 + slot_]; \
    const bf8v af2 = *(const bf8v*)&As[(32 + m15) * 256 + slot_]; \
    const bf8v af3 = *(const bf8v*)&As[(48 + m15) * 256 + slot_]; \
    __builtin_amdgcn_s_setprio(1); \
    MFMA4(0, af0, sl) \
    MFMA4(1, af1, sl) \
    MFMA4(2, af2, sl) \
    MFMA4(3, af3, sl) \
    __builtin_amdgcn_s_setprio(0); }

#define EPI(pp) { \
    const int by_ = nb * 4 + (pp); \
    const int gsl_ = wc * 4 + (m15 >> 2); \
    const float e0_ = en_lds[(pp) * 256 + wc * 64 +  0 + m15]; \
    const float e1_ = en_lds[(pp) * 256 + wc * 64 + 16 + m15]; \
    const float e2_ = en_lds[(pp) * 256 + wc * 64 + 32 + m15]; \
    const float e3_ = en_lds[(pp) * 256 + wc * 64 + 48 + m15]; \
    _Pragma("unroll") \
    for (int rt = 0; rt < 4; rt++) { \
        float sv[4]; \
        _Pragma("unroll") \
        for (int j = 0; j < 4; j++) { \
            float s_ = fmaf(-2.f, acc[rt][0][j], e0_); \
            s_ = fminf(s_, fmaf(-2.f, acc[rt][1][j], e1_)); \
            s_ = fminf(s_, fmaf(-2.f, acc[rt][2][j], e2_)); \
            s_ = fminf(s_, fmaf(-2.f, acc[rt][3][j], e3_)); \
            sv[j] = s_; \
        } \
        _Pragma("unroll") \
        for (int m = 1; m <= 2; m <<= 1) { \
            _Pragma("unroll") \
            for (int j = 0; j < 4; j++) sv[j] = fminf(sv[j], __shfl_xor(sv[j], m, 64)); \
        } \
        if ((m15 & 3) == 0) { \
            const int rl_ = rt * 16 + q * 4; \
            _Pragma("unroll") \
            for (int j = 0; j < 4; j++) \
                sm[(rl_ + j) * 16 + gsl_] = __half_as_ushort(__float2half_rn(sv[j])); \
        } \
    } \
    asm volatile("s_waitcnt lgkmcnt(0)" ::: "memory"); \
    __builtin_amdgcn_sched_barrier(0); \
    __builtin_amdgcn_s_barrier(); \
    __builtin_amdgcn_sched_barrier(0); \
    if (t < 128) { \
        const uint4 v_ = *(const uint4*)&sm[t * 8]; \
        *(uint4*)&pvalh[(size_t)(row0 + (t >> 1)) * 1024 + by_ * 16 + (t & 1) * 8] = v_; \
    } \
    __builtin_amdgcn_sched_barrier(0); \
    __builtin_amdgcn_s_barrier(); \
    __builtin_amdgcn_sched_barrier(0); \
    _Pragma("unroll") \
    for (int rt = 0; rt < 4; rt++) { \
        _Pragma("unroll") \
        for (int ct = 0; ct < 4; ct++) acc[rt][ct] = (f4v){0.f, 0.f, 0.f, 0.f}; \
    } }

__global__ __launch_bounds__(256, 3) void k_score(
        const unsigned short* __restrict__ zb, const unsigned short* __restrict__ eb,
        const float* __restrict__ enorm, unsigned short* __restrict__ pvalh) {
    __shared__ unsigned short As[64 * 256];   // 32 KB, swizzled: slot = chunk ^ (r&15)
    __shared__ unsigned short sm[64 * 16];    // 2 KB
    __shared__ float en_lds[1024];            // 4 KB: enorm for this block's 4 panels
    const int rx = blockIdx.x & 127;          // 128 row-tiles
    const int nb = blockIdx.x >> 7;           // 16 panel-quads (4 panels each)
    const int row0 = rx * 64;
    const int t = threadIdx.x;
    const int lane = t & 63, wc = t >> 6;
    const int q = lane >> 4, m15 = lane & 15;

    // ---- stage A (64x256 bf16, swizzled) ----
#pragma unroll
    for (int j = 0; j < 8; j++) {
        const int id = j * 256 + t;
        const int r = id >> 5, sl = id & 31;
        const int c = sl ^ (r & 15);
        __builtin_amdgcn_global_load_lds(
            (const __attribute__((address_space(1))) void*)(zb + (size_t)(row0 + r) * DIM + c * 8),
            (__attribute__((address_space(3))) void*)((char*)As + id * 16), 16, 0, 0);
    }
    // ---- stage enorm for the 4 panels (1024 floats, linear) ----
#pragma unroll
    for (int j = 0; j < 4; j++) {
        __builtin_amdgcn_global_load_lds(
            (const __attribute__((address_space(1))) void*)(enorm + nb * 1024 + j * 256 + t),
            (__attribute__((address_space(3))) void*)((char*)en_lds + (j * 256 + t) * 4), 4, 0, 0);
    }
    __syncthreads();   // drains vmcnt(0): all staging -> clean slate for counted waits

    f4v acc[4][4];
#pragma unroll
    for (int rt = 0; rt < 4; rt++)
#pragma unroll
        for (int ct = 0; ct < 4; ct++) acc[rt][ct] = (f4v){0.f, 0.f, 0.f, 0.f};

    const unsigned voffb0 = (unsigned)(((nb * 1024 + wc * 64 +  0 + m15) * DIM + q * 8) * 2);
    const unsigned voffb1 = (unsigned)(((nb * 1024 + wc * 64 + 16 + m15) * DIM + q * 8) * 2);
    const unsigned voffb2 = (unsigned)(((nb * 1024 + wc * 64 + 32 + m15) * DIM + q * 8) * 2);
    const unsigned voffb3 = (unsigned)(((nb * 1024 + wc * 64 + 48 + m15) * DIM + q * 8) * 2);

    bf8v Bp0_0, Bp0_1, Bp0_2, Bp0_3;
    bf8v Bp1_0, Bp1_1, Bp1_2, Bp1_3;
    bf8v Bp2_0, Bp2_1, Bp2_2, Bp2_3;

    // prologue: stages 0,1,2 (12 loads in flight)
    ISSUE(0, 0) ISSUE(1, 1) ISSUE(2, 2)

    // ---- panel 0 (K 0..7) ----
    STEP(0, 0, 8) ISSUE(0, 3)
    STEP(1, 1, 8) ISSUE(1, 4)
    STEP(2, 2, 8) ISSUE(2, 5)
    STEP(3, 0, 8) ISSUE(0, 6)
    STEP(4, 1, 8) ISSUE(1, 7)
    STEP(5, 2, 8) ISSUE(2, 8)
    STEP(6, 0, 8) ISSUE(0, 9)
    STEP(7, 1, 8) ISSUE(1, 10)
    EPI(0)
    // ---- panel 1 (K 8..15) ----
    STEP(0, 2, 8) ISSUE(2, 11)
    STEP(1, 0, 8) ISSUE(0, 12)
    STEP(2, 1, 8) ISSUE(1, 13)
    STEP(3, 2, 8) ISSUE(2, 14)
    STEP(4, 0, 8) ISSUE(0, 15)
    STEP(5, 1, 8) ISSUE(1, 16)
    STEP(6, 2, 8) ISSUE(2, 17)
    STEP(7, 0, 8) ISSUE(0, 18)
    EPI(1)
    // ---- panel 2 (K 16..23) ----
    STEP(0, 1, 8) ISSUE(1, 19)
    STEP(1, 2, 8) ISSUE(2, 20)
    STEP(2, 0, 8) ISSUE(0, 21)
    STEP(3, 1, 8) ISSUE(1, 22)
    STEP(4, 2, 8) ISSUE(2, 23)
    STEP(5, 0, 8) ISSUE(0, 24)
    STEP(6, 1, 8) ISSUE(1, 25)
    STEP(7, 2, 8) ISSUE(2, 26)
    EPI(2)
    // ---- panel 3 (K 24..31) ----
    STEP(0, 0, 8) ISSUE(0, 27)
    STEP(1, 1, 8) ISSUE(1, 28)
    STEP(2, 2, 8) ISSUE(2, 29)
    STEP(3, 0, 8) ISSUE(0, 30)
    STEP(4, 1, 8) ISSUE(1, 31)
    STEP(5, 2, 8)
    STEP(6, 0, 4)
    STEP(7, 1, 0)
    EPI(3)
}

// ---------------- select: per-row flag + exact fp32 rescore + argmin ----------------
__global__ __launch_bounds__(256) void k_select(
        const float* __restrict__ zf, const float* __restrict__ emb,
        const float* __restrict__ enorm, const unsigned short* __restrict__ pvalh,
        int* __restrict__ idxi, float* __restrict__ out_idx) {
    const int row = blockIdx.x;
    const int t = threadIdx.x;
    const int lane = t & 63, w = t >> 6;
    __shared__ float zs[256];
    __shared__ float wred[4];
    __shared__ int lcnt;
    __shared__ int list[1024];
    __shared__ float fs[16];
    __shared__ int fi[16];

    const float zv = zf[(size_t)row * DIM + t];
    zs[t] = zv;
    if (t == 0) lcnt = 0;
    float nrm = zv * zv;
#pragma unroll
    for (int m = 1; m < 64; m <<= 1) nrm += __shfl_xor(nrm, m, 64);
    if (lane == 0) wred[w] = nrm;

    const __half* p = (const __half*)(pvalh + (size_t)row * 1024 + t * 4);
    float v[4];
#pragma unroll
    for (int k = 0; k < 4; k++) v[k] = __half2float(p[k]);
    float mn = fminf(fminf(v[0], v[1]), fminf(v[2], v[3]));
#pragma unroll
    for (int m = 1; m < 64; m <<= 1) mn = fminf(mn, __shfl_xor(mn, m, 64));
    __shared__ float wmin[4];
    if (lane == 0) wmin[w] = mn;
    __syncthreads();
    const float zn = wred[0] + wred[1] + wred[2] + wred[3];
    const float g = fminf(fminf(wmin[0], wmin[1]), fminf(wmin[2], wmin[3])) + MARGIN;
#pragma unroll
    for (int k = 0; k < 4; k++) {
        if (v[k] <= g) {
            const int pos = atomicAdd(&lcnt, 1);
            list[pos] = t * 4 + k;
        }
    }
    __syncthreads();

    const int lane16 = t & 15, codei = t >> 4;
    const int n = lcnt;
    float bv = 3.0e38f;
    int bi = 0x7fffffff;
    for (int i = 0; i < n; i++) {
        const int gg = list[i];
        const int cbase = ((gg >> 4) << 8) + (((gg >> 2) & 3) << 6) + ((gg & 3) << 2);
        const int code = cbase + ((codei >> 2) << 4) + (codei & 3);
        const float* zp = zs + lane16 * 16;
        const float* ep = emb + (size_t)code * DIM + lane16 * 16;
        float d = 0.f;
#pragma unroll
        for (int k = 0; k < 16; k += 4) {
            const float4 ev = *(const float4*)(ep + k);
            const float4 zv4 = *(const float4*)(zp + k);
            d = fmaf(zv4.x, ev.x, d);
            d = fmaf(zv4.y, ev.y, d);
            d = fmaf(zv4.z, ev.z, d);
            d = fmaf(zv4.w, ev.w, d);
        }
#pragma unroll
        for (int m = 1; m <= 8; m <<= 1) d += __shfl_xor(d, m, 64);
        if (lane16 == 0) {
            const float tt = zn + enorm[code];
            const float s = tt - 2.0f * d;
            if (s < bv || (s == bv && code < bi)) { bv = s; bi = code; }
        }
    }
    if (lane16 == 0) { fs[codei] = bv; fi[codei] = bi; }
    __syncthreads();
    if (t == 0) {
        float b = fs[0]; int c = fi[0];
#pragma unroll
        for (int k = 1; k < 16; k++)
            if (fs[k] < b || (fs[k] == b && fi[k] < c)) { b = fs[k]; c = fi[k]; }
        idxi[row] = c;
        out_idx[row] = (float)c;
    }
}

// ---------------- gather z_q (NCHW) + fused loss (atomicAdd) ----------------
__global__ __launch_bounds__(256) void k_gather(const float* __restrict__ emb,
                                                const float* __restrict__ zf,
                                                const int* __restrict__ idxi,
                                                float* __restrict__ zq,
                                                float* __restrict__ out_loss) {
    __shared__ float t[32][33];
    const int hw0 = blockIdx.x * 32;
    const int c0  = blockIdx.y * 32;
    const int b   = blockIdx.z;
    const int tx = threadIdx.x & 31, ty = threadIdx.x >> 5;
    float lsum = 0.f;
#pragma unroll
    for (int i = 0; i < 4; i++) {
        const int hh = ty + 8 * i;
        const int n = b * 1024 + hw0 + hh;
        const int id = idxi[n];
        const float q = emb[(size_t)id * DIM + c0 + tx];
        const float zv = zf[(size_t)n * DIM + c0 + tx];
        const float d = q - zv;
        lsum += d * d;
        t[hh][tx] = q;
    }
    __syncthreads();
#pragma unroll
    for (int i = 0; i < 4; i++) {
        const int c = c0 + ty + 8 * i;
        zq[(size_t)(b * 256 + c) * 1024 + hw0 + tx] = t[tx][ty + 8 * i];
    }
#pragma unroll
    for (int m = 1; m < 64; m <<= 1) lsum += __shfl_xor(lsum, m, 64);
    __shared__ float wsum[4];
    const int lane = threadIdx.x & 63, w = threadIdx.x >> 6;
    if (lane == 0) wsum[w] = lsum;
    __syncthreads();
    if (threadIdx.x == 0) {
        const float total = wsum[0] + wsum[1] + wsum[2] + wsum[3];
        atomicAdd(out_loss, total * (1.25f / 2097152.0f));
    }
}

extern "C" void kernel_launch(void* const* d_in, const int* in_sizes, int n_in,
                              void* d_out, int out_size, void* d_ws, size_t ws_size,
                              hipStream_t stream) {
    const float* z   = (const float*)d_in[0];   // [8,256,32,32]
    const float* emb = (const float*)d_in[1];   // [16384,256]
    float* out = (float*)d_out;
    float* ws  = (float*)d_ws;

    float*          zf    = ws;                                   // 2,097,152 floats (8 MB)
    unsigned short* pvalh = (unsigned short*)(ws + 2097152);      // 8M halves (16 MB)
    unsigned short* zb    = (unsigned short*)(ws + 6291456);      // 2M halves (4 MB)
    unsigned short* eb    = (unsigned short*)(ws + 7340032);      // 4M halves (8 MB)
    float*          enorm = ws + 9437184;                         // 16,384
    int*            idxi  = (int*)(ws + 9453568);                 // 8,192

    float* zq       = out;                   // [8,256,32,32] NCHW
    float* out_loss = out + 2097152;         // scalar
    float* out_idx  = out + 2097153;         // [8192] as float32

    k_prep<<<dim3(6145), 256, 0, stream>>>(z, emb, zf, zb, eb, enorm, out_loss);
    k_score<<<dim3(2048), 256, 0, stream>>>(zb, eb, enorm, pvalh);
    k_select<<<dim3(8192), 256, 0, stream>>>(zf, emb, enorm, pvalh, idxi, out_idx);
    k_gather<<<dim3(32, 8, 8), 256, 0, stream>>>(emb, zf, idxi, zq, out_loss);
}